// Round 2
// baseline (633.771 us; speedup 1.0000x reference)
//
#include <hip/hip_runtime.h>
#include <cstdint>
#include <cstddef>

#define L_SEQ 2048
#define BATCH 8
#define DIN   1024
#define PDIM  512
#define DOUT  1024
#define MROWS (L_SEQ * BATCH)   // 16384

typedef __attribute__((ext_vector_type(4))) float f32x4;
typedef __attribute__((ext_vector_type(8))) short bf16x8;
typedef __attribute__((ext_vector_type(4))) unsigned int u32x4;

__device__ __forceinline__ unsigned short f2bf(float f) {
  union { float f; unsigned int u; } v; v.f = f;
  unsigned int u = v.u;
  unsigned int r = (u + 0x7FFFu + ((u >> 16) & 1u)) >> 16;
  return (unsigned short)r;
}
__device__ __forceinline__ float bf2f(unsigned short h) {
  union { unsigned int u; float f; } v; v.u = ((unsigned int)h) << 16;
  return v.f;
}

// async global->LDS, 16 bytes per lane; dest is wave-uniform base + lane*16
__device__ __forceinline__ void gld16(const unsigned short* g, unsigned short* l) {
  __builtin_amdgcn_global_load_lds(
      (const __attribute__((address_space(1))) void*)g,
      (__attribute__((address_space(3))) void*)l,
      16, 0, 0);
}

// ---------------- fp32 -> bf16 convert (vectorized) ----------------
__global__ void convert_f32_bf16(const float* __restrict__ in,
                                 unsigned short* __restrict__ out, int n4) {
  int i = blockIdx.x * blockDim.x + threadIdx.x;
  int stride = gridDim.x * blockDim.x;
  for (; i < n4; i += stride) {
    float4 v = reinterpret_cast<const float4*>(in)[i];
    ushort4 o;
    o.x = f2bf(v.x); o.y = f2bf(v.y); o.z = f2bf(v.z); o.w = f2bf(v.w);
    reinterpret_cast<ushort4*>(out)[i] = o;
  }
}

// ---------------- V transpose: kv[l][b][512+p] -> vt[b][p][l] ----------------
__global__ void transpose_v_kernel(const unsigned short* __restrict__ kv,
                                   unsigned short* __restrict__ vt) {
  __shared__ unsigned short tile[32][33];
  int b = blockIdx.z;
  int l0 = blockIdx.x * 32;
  int p0 = blockIdx.y * 32;
  const unsigned short* src = kv + (size_t)b * (2 * PDIM) + PDIM;
  unsigned short* dst = vt + (size_t)b * PDIM * L_SEQ;
  int tx = threadIdx.x, ty = threadIdx.y;
  #pragma unroll
  for (int r = ty; r < 32; r += 8)
    tile[r][tx] = src[(size_t)(l0 + r) * (BATCH * 2 * PDIM) + p0 + tx];
  __syncthreads();
  #pragma unroll
  for (int r = ty; r < 32; r += 8)
    dst[(size_t)(p0 + r) * L_SEQ + l0 + tx] = tile[tx][r];
}

// ---------------- row softmax with causal mask ----------------
__global__ void softmax_causal(const float* __restrict__ S,
                               unsigned short* __restrict__ P,
                               size_t sStrideB, size_t pStrideB, float scale) {
  __shared__ float buf[L_SEQ];
  __shared__ float red[4];
  int b = blockIdx.z;
  int i = blockIdx.x;                       // causal row index within batch
  const float* srow = S + b * sStrideB + (size_t)i * L_SEQ;
  unsigned short* prow = P + b * pStrideB + (size_t)i * L_SEQ;
  int t = threadIdx.x;
  int lane = t & 63, wid = t >> 6;

  float lmax = -3.0e38f;
  for (int j = t; j <= i; j += 256) {
    float v = srow[j] * scale;
    buf[j] = v;
    lmax = fmaxf(lmax, v);
  }
  #pragma unroll
  for (int o = 32; o > 0; o >>= 1) lmax = fmaxf(lmax, __shfl_xor(lmax, o));
  if (lane == 0) red[wid] = lmax;
  __syncthreads();
  float m = fmaxf(fmaxf(red[0], red[1]), fmaxf(red[2], red[3]));

  float lsum = 0.0f;
  for (int j = t; j <= i; j += 256) {
    float e = __expf(buf[j] - m);
    buf[j] = e;
    lsum += e;
  }
  #pragma unroll
  for (int o = 32; o > 0; o >>= 1) lsum += __shfl_xor(lsum, o);
  __syncthreads();                           // red reuse
  if (lane == 0) red[wid] = lsum;
  __syncthreads();
  float inv = 1.0f / (red[0] + red[1] + red[2] + red[3]);

  // PV's causal K-limit only ever reads up to the next 128-aligned boundary
  int jmax = ((i >> 7) + 1) << 7;
  for (int j = t; j < jmax; j += 256)
    prow[j] = (j <= i) ? f2bf(buf[j] * inv) : (unsigned short)0;
}

// ---------------- bf16 MFMA GEMM: C[M,N] = A[M,K] @ B[N,K]^T ----------------
// m97 structure: linear LDS + global_load_lds(16B) staging.
// EPI: 0 = store bf16, 1 = store fp32, 2 = store bf16 with residual add (R)
#define BM 128
#define BN 128
#define BK 64

template<int EPI>
__global__ __launch_bounds__(256)
void gemm_bt(const unsigned short* __restrict__ A,
             const unsigned short* __restrict__ B,
             void* __restrict__ C,
             const unsigned short* __restrict__ R,
             int M, int N, int K, int lda, int ldb, int ldc,
             size_t sAb, size_t sBb, size_t sCb, size_t sRb,
             int skipUpper, int causalK) {
  int tm = blockIdx.y * BM;
  int tn = blockIdx.x * BN;
  if (skipUpper && tn >= tm + BM) return;    // fully-masked causal tile

  int bz = blockIdx.z;
  A += (size_t)bz * sAb;
  B += (size_t)bz * sBb;
  R += (size_t)bz * sRb;
  float* Cf = (float*)C + (size_t)bz * sCb;
  unsigned short* Ch = (unsigned short*)C + (size_t)bz * sCb;

  __shared__ unsigned short As[BM * BK];   // linear [128][64]
  __shared__ unsigned short Bs[BN * BK];

  int t = threadIdx.x;
  int lane = t & 63;
  int wid = t >> 6;
  int wr = (wid >> 1) * 64;
  int wc = (wid & 1) * 64;
  int lr = lane & 15;
  int kof = (lane >> 4) * 8;

  f32x4 acc[4][4];
  f32x4 zero = {0.0f, 0.0f, 0.0f, 0.0f};
  #pragma unroll
  for (int m = 0; m < 4; ++m)
    #pragma unroll
    for (int n = 0; n < 4; ++n) acc[m][n] = zero;

  int kEnd = causalK ? ((tm + BM) < K ? (tm + BM) : K) : K;

  // staging geometry: wave wid owns rows [wid*32, wid*32+32), 8 rows per load
  int srow = lane >> 3;          // 0..7 within the 8-row group
  int scol = (lane & 7) * 8;     // element col, 8 bf16 = 16B per lane

  for (int k0 = 0; k0 < kEnd; k0 += BK) {
    #pragma unroll
    for (int it = 0; it < 4; ++it) {
      int r = wid * 32 + it * 8;
      gld16(A + (size_t)(tm + r + srow) * lda + k0 + scol, &As[r * BK]);
      gld16(B + (size_t)(tn + r + srow) * ldb + k0 + scol, &Bs[r * BK]);
    }
    __syncthreads();
    #pragma unroll
    for (int kk = 0; kk < BK; kk += 32) {
      bf16x8 af[4], bfr[4];
      #pragma unroll
      for (int m = 0; m < 4; ++m)
        af[m] = *(const bf16x8*)&As[(wr + m * 16 + lr) * BK + kk + kof];
      #pragma unroll
      for (int n = 0; n < 4; ++n)
        bfr[n] = *(const bf16x8*)&Bs[(wc + n * 16 + lr) * BK + kk + kof];
      #pragma unroll
      for (int m = 0; m < 4; ++m)
        #pragma unroll
        for (int n = 0; n < 4; ++n)
          acc[m][n] = __builtin_amdgcn_mfma_f32_16x16x32_bf16(af[m], bfr[n], acc[m][n], 0, 0, 0);
    }
    __syncthreads();
  }

  int rb0 = tm + wr + (lane >> 4) * 4;       // C/D: col=lane&15, row=(lane>>4)*4+j
  #pragma unroll
  for (int m = 0; m < 4; ++m) {
    #pragma unroll
    for (int n = 0; n < 4; ++n) {
      int col = tn + wc + n * 16 + lr;
      #pragma unroll
      for (int j = 0; j < 4; ++j) {
        int row = rb0 + m * 16 + j;
        float v = acc[m][n][j];
        size_t idx = (size_t)row * ldc + col;
        if constexpr (EPI == 1) {
          Cf[idx] = v;
        } else if constexpr (EPI == 2) {
          Ch[idx] = f2bf(v + bf2f(R[idx]));
        } else {
          Ch[idx] = f2bf(v);
        }
      }
    }
  }
}

// ---------------- fallback sentinel ----------------
__global__ void fill_kernel(float* out, int n, float v) {
  int i = blockIdx.x * blockDim.x + threadIdx.x;
  for (; i < n; i += gridDim.x * blockDim.x) out[i] = v;
}

extern "C" void kernel_launch(void* const* d_in, const int* in_sizes, int n_in,
                              void* d_out, int out_size, void* d_ws, size_t ws_size,
                              hipStream_t stream) {
  const float* x  = (const float*)d_in[0];
  const float* W1 = (const float*)d_in[1];
  const float* W2 = (const float*)d_in[2];
  const float* W3 = (const float*)d_in[3];
  float* out = (float*)d_out;

  char* ws = (char*)d_ws;
  size_t off = 0;
  auto alloc = [&](size_t bytes) -> char* {
    char* p = ws + off;
    off += (bytes + 255) & ~(size_t)255;
    return p;
  };

  unsigned short* xb  = (unsigned short*)alloc((size_t)MROWS * DIN * 2);
  unsigned short* w1b = (unsigned short*)alloc((size_t)PDIM * DIN * 2);
  unsigned short* w2b = (unsigned short*)alloc((size_t)2 * PDIM * PDIM * 2);
  unsigned short* w3b = (unsigned short*)alloc((size_t)DOUT * PDIM * 2);
  unsigned short* zb  = (unsigned short*)alloc((size_t)MROWS * PDIM * 2);
  unsigned short* kvb = (unsigned short*)alloc((size_t)MROWS * 2 * PDIM * 2);
  unsigned short* vt  = (unsigned short*)alloc((size_t)BATCH * PDIM * L_SEQ * 2);
  unsigned short* ar  = (unsigned short*)alloc((size_t)MROWS * PDIM * 2);

  size_t scoresFull = (size_t)BATCH * L_SEQ * L_SEQ * 4;
  size_t probsFull  = (size_t)BATCH * L_SEQ * L_SEQ * 2;
  size_t scores1    = (size_t)L_SEQ * L_SEQ * 4;
  size_t probs1     = (size_t)L_SEQ * L_SEQ * 2;

  size_t seqNeed  = off + scores1 + probs1;
  size_t fullNeed = off + scoresFull + probsFull;

  if (ws_size < seqNeed) {
    float sentinel = 1.0e6f + (float)(ws_size >> 20);
    fill_kernel<<<512, 256, 0, stream>>>(out, out_size, sentinel);
    return;
  }
  bool full = (ws_size >= fullNeed);

  float* scores;
  unsigned short* probs;
  if (full) {
    scores = (float*)alloc(scoresFull);
    probs  = (unsigned short*)alloc(probsFull);
  } else {
    scores = (float*)alloc(scores1);
    probs  = (unsigned short*)alloc(probs1);
  }

  const float scaling = 0.04419417382415922f;  // 512^-0.5

  // converts
  convert_f32_bf16<<<2048, 256, 0, stream>>>(x,  xb,  (MROWS * DIN) / 4);
  convert_f32_bf16<<<512,  256, 0, stream>>>(W1, w1b, (PDIM * DIN) / 4);
  convert_f32_bf16<<<512,  256, 0, stream>>>(W2, w2b, (2 * PDIM * PDIM) / 4);
  convert_f32_bf16<<<512,  256, 0, stream>>>(W3, w3b, (DOUT * PDIM) / 4);

  // GEMM1: z = x @ W1^T   [16384,1024]x[512,1024] -> [16384,512] bf16
  gemm_bt<0><<<dim3(PDIM / BN, MROWS / BM, 1), 256, 0, stream>>>(
      xb, w1b, zb, zb, MROWS, PDIM, DIN, DIN, DIN, PDIM, 0, 0, 0, 0, 0, 0);

  // GEMM2: kv = z @ W2^T  [16384,512]x[1024,512] -> [16384,1024] bf16
  gemm_bt<0><<<dim3(2 * PDIM / BN, MROWS / BM, 1), 256, 0, stream>>>(
      zb, w2b, kvb, zb, MROWS, 2 * PDIM, PDIM, PDIM, PDIM, 2 * PDIM, 0, 0, 0, 0, 0, 0);

  // V transpose per batch: vt[b][p][l]
  transpose_v_kernel<<<dim3(L_SEQ / 32, PDIM / 32, BATCH), dim3(32, 8), 0, stream>>>(kvb, vt);

  if (full) {
    // scores[b] = Q_b @ K_b^T  (fp32), causal tile skip
    gemm_bt<1><<<dim3(L_SEQ / BN, L_SEQ / BM, BATCH), 256, 0, stream>>>(
        zb, kvb, scores, zb, L_SEQ, L_SEQ, PDIM,
        BATCH * PDIM, BATCH * 2 * PDIM, L_SEQ,
        (size_t)PDIM, (size_t)2 * PDIM, (size_t)L_SEQ * L_SEQ, 0, 1, 0);
    softmax_causal<<<dim3(L_SEQ, 1, BATCH), 256, 0, stream>>>(
        scores, probs, (size_t)L_SEQ * L_SEQ, (size_t)L_SEQ * L_SEQ, scaling);
    // attn_out + residual -> ar (bf16), causal K-limit
    gemm_bt<2><<<dim3(PDIM / BN, L_SEQ / BM, BATCH), 256, 0, stream>>>(
        probs, vt, ar, zb, L_SEQ, PDIM, L_SEQ,
        L_SEQ, L_SEQ, BATCH * PDIM,
        (size_t)L_SEQ * L_SEQ, (size_t)PDIM * L_SEQ, (size_t)PDIM, (size_t)PDIM, 0, 1);
  } else {
    for (int b = 0; b < BATCH; ++b) {
      gemm_bt<1><<<dim3(L_SEQ / BN, L_SEQ / BM, 1), 256, 0, stream>>>(
          zb + (size_t)b * PDIM, kvb + (size_t)b * 2 * PDIM, scores, zb,
          L_SEQ, L_SEQ, PDIM, BATCH * PDIM, BATCH * 2 * PDIM, L_SEQ,
          0, 0, 0, 0, 1, 0);
      softmax_causal<<<dim3(L_SEQ, 1, 1), 256, 0, stream>>>(
          scores, probs, 0, 0, scaling);
      gemm_bt<2><<<dim3(PDIM / BN, L_SEQ / BM, 1), 256, 0, stream>>>(
          probs, vt + (size_t)b * PDIM * L_SEQ, ar + (size_t)b * PDIM, zb + (size_t)b * PDIM,
          L_SEQ, PDIM, L_SEQ, L_SEQ, L_SEQ, BATCH * PDIM,
          0, 0, 0, 0, 0, 1);
    }
  }

  // GEMM3: out = (attn + residual) @ W3^T -> fp32 d_out
  gemm_bt<1><<<dim3(DOUT / BN, MROWS / BM, 1), 256, 0, stream>>>(
      ar, w3b, out, zb, MROWS, DOUT, PDIM, PDIM, PDIM, DOUT, 0, 0, 0, 0, 0, 0);
}

// Round 3
// 321.398 us; speedup vs baseline: 1.9719x; 1.9719x over previous
//
#include <hip/hip_runtime.h>
#include <cstdint>
#include <cstddef>

#define L_SEQ 2048
#define BATCH 8
#define DIN   1024
#define PDIM  512
#define DOUT  1024
#define MROWS (L_SEQ * BATCH)   // 16384

typedef __attribute__((ext_vector_type(4))) float f32x4;
typedef __attribute__((ext_vector_type(8))) short bf16x8;
typedef __attribute__((ext_vector_type(4))) unsigned int u32x4;

__device__ __forceinline__ unsigned short f2bf(float f) {
  union { float f; unsigned int u; } v; v.f = f;
  unsigned int u = v.u;
  unsigned int r = (u + 0x7FFFu + ((u >> 16) & 1u)) >> 16;
  return (unsigned short)r;
}
__device__ __forceinline__ float bf2f(unsigned short h) {
  union { unsigned int u; float f; } v; v.u = ((unsigned int)h) << 16;
  return v.f;
}

// async global->LDS, 16 bytes per lane; dest is wave-uniform base + lane*16
__device__ __forceinline__ void gld16(const unsigned short* g, unsigned short* l) {
  __builtin_amdgcn_global_load_lds(
      (const __attribute__((address_space(1))) void*)g,
      (__attribute__((address_space(3))) void*)l,
      16, 0, 0);
}

// ---------------- fp32 -> bf16 convert (vectorized) ----------------
__global__ void convert_f32_bf16(const float* __restrict__ in,
                                 unsigned short* __restrict__ out, int n4) {
  int i = blockIdx.x * blockDim.x + threadIdx.x;
  int stride = gridDim.x * blockDim.x;
  for (; i < n4; i += stride) {
    float4 v = reinterpret_cast<const float4*>(in)[i];
    ushort4 o;
    o.x = f2bf(v.x); o.y = f2bf(v.y); o.z = f2bf(v.z); o.w = f2bf(v.w);
    reinterpret_cast<ushort4*>(out)[i] = o;
  }
}

// ---------------- V transpose: kv[l][b][512+p] -> vt[b][p][l] ----------------
__global__ void transpose_v_kernel(const unsigned short* __restrict__ kv,
                                   unsigned short* __restrict__ vt) {
  __shared__ unsigned short tile[32][33];
  int b = blockIdx.z;
  int l0 = blockIdx.x * 32;
  int p0 = blockIdx.y * 32;
  const unsigned short* src = kv + (size_t)b * (2 * PDIM) + PDIM;
  unsigned short* dst = vt + (size_t)b * PDIM * L_SEQ;
  int tx = threadIdx.x, ty = threadIdx.y;
  #pragma unroll
  for (int r = ty; r < 32; r += 8)
    tile[r][tx] = src[(size_t)(l0 + r) * (BATCH * 2 * PDIM) + p0 + tx];
  __syncthreads();
  #pragma unroll
  for (int r = ty; r < 32; r += 8)
    dst[(size_t)(p0 + r) * L_SEQ + l0 + tx] = tile[tx][r];
}

// ---------------- row softmax with causal mask ----------------
__global__ void softmax_causal(const float* __restrict__ S,
                               unsigned short* __restrict__ P,
                               size_t sStrideB, size_t pStrideB, float scale) {
  __shared__ float buf[L_SEQ];
  __shared__ float red[4];
  int b = blockIdx.z;
  int i = blockIdx.x;                       // causal row index
  const float* srow = S + b * sStrideB + (size_t)i * L_SEQ;
  unsigned short* prow = P + b * pStrideB + (size_t)i * L_SEQ;
  int t = threadIdx.x;
  int lane = t & 63, wid = t >> 6;

  float lmax = -3.0e38f;
  for (int j = t; j <= i; j += 256) {
    float v = srow[j] * scale;
    buf[j] = v;
    lmax = fmaxf(lmax, v);
  }
  #pragma unroll
  for (int o = 32; o > 0; o >>= 1) lmax = fmaxf(lmax, __shfl_xor(lmax, o));
  if (lane == 0) red[wid] = lmax;
  __syncthreads();
  float m = fmaxf(fmaxf(red[0], red[1]), fmaxf(red[2], red[3]));

  float lsum = 0.0f;
  for (int j = t; j <= i; j += 256) {
    float e = __expf(buf[j] - m);
    buf[j] = e;
    lsum += e;
  }
  #pragma unroll
  for (int o = 32; o > 0; o >>= 1) lsum += __shfl_xor(lsum, o);
  __syncthreads();
  if (lane == 0) red[wid] = lsum;
  __syncthreads();
  float inv = 1.0f / (red[0] + red[1] + red[2] + red[3]);

  // PV's causal K-limit only ever reads up to the next 128-aligned boundary
  int jmax = ((i >> 7) + 1) << 7;
  for (int j = t; j < jmax; j += 256)
    prow[j] = (j <= i) ? f2bf(buf[j] * inv) : (unsigned short)0;
}

// ---------------- bf16 MFMA GEMM: C[M,N] = A[M,K] @ B[N,K]^T ----------------
// m97 structure: linear LDS + global_load_lds(16B) staging.
// EPI: 0 = store bf16, 1 = store fp32, 2 = store bf16 with residual add (R)
#define BM 128
#define BN 128
#define BK 64

template<int EPI>
__global__ __launch_bounds__(256)
void gemm_bt(const unsigned short* __restrict__ A,
             const unsigned short* __restrict__ B,
             void* __restrict__ C,
             const unsigned short* __restrict__ R,
             int M, int N, int K, int lda, int ldb, int ldc,
             size_t sAb, size_t sBb, size_t sCb, size_t sRb,
             int skipUpper, int causalK) {
  int tm = blockIdx.y * BM;
  int tn = blockIdx.x * BN;
  if (skipUpper && tn >= tm + BM) return;    // fully-masked causal tile

  int bz = blockIdx.z;
  A += (size_t)bz * sAb;
  B += (size_t)bz * sBb;
  R += (size_t)bz * sRb;
  float* Cf = (float*)C + (size_t)bz * sCb;
  unsigned short* Ch = (unsigned short*)C + (size_t)bz * sCb;

  __shared__ unsigned short As[BM * BK];   // linear [128][64]
  __shared__ unsigned short Bs[BN * BK];

  int t = threadIdx.x;
  int lane = t & 63;
  int wid = t >> 6;
  int wr = (wid >> 1) * 64;
  int wc = (wid & 1) * 64;
  int lr = lane & 15;
  int kof = (lane >> 4) * 8;

  f32x4 acc[4][4];
  f32x4 zero = {0.0f, 0.0f, 0.0f, 0.0f};
  #pragma unroll
  for (int m = 0; m < 4; ++m)
    #pragma unroll
    for (int n = 0; n < 4; ++n) acc[m][n] = zero;

  int kEnd = causalK ? ((tm + BM) < K ? (tm + BM) : K) : K;

  // staging geometry: wave wid owns rows [wid*32, wid*32+32), 8 rows per load
  int srow = lane >> 3;          // 0..7 within the 8-row group
  int scol = (lane & 7) * 8;     // element col, 8 bf16 = 16B per lane

  for (int k0 = 0; k0 < kEnd; k0 += BK) {
    #pragma unroll
    for (int it = 0; it < 4; ++it) {
      int r = wid * 32 + it * 8;
      gld16(A + (size_t)(tm + r + srow) * lda + k0 + scol, &As[r * BK]);
      gld16(B + (size_t)(tn + r + srow) * ldb + k0 + scol, &Bs[r * BK]);
    }
    __syncthreads();
    #pragma unroll
    for (int kk = 0; kk < BK; kk += 32) {
      bf16x8 af[4], bfr[4];
      #pragma unroll
      for (int m = 0; m < 4; ++m)
        af[m] = *(const bf16x8*)&As[(wr + m * 16 + lr) * BK + kk + kof];
      #pragma unroll
      for (int n = 0; n < 4; ++n)
        bfr[n] = *(const bf16x8*)&Bs[(wc + n * 16 + lr) * BK + kk + kof];
      #pragma unroll
      for (int m = 0; m < 4; ++m)
        #pragma unroll
        for (int n = 0; n < 4; ++n)
          acc[m][n] = __builtin_amdgcn_mfma_f32_16x16x32_bf16(af[m], bfr[n], acc[m][n], 0, 0, 0);
    }
    __syncthreads();
  }

  int rb0 = tm + wr + (lane >> 4) * 4;       // C/D: col=lane&15, row=(lane>>4)*4+j
  #pragma unroll
  for (int m = 0; m < 4; ++m) {
    #pragma unroll
    for (int n = 0; n < 4; ++n) {
      int col = tn + wc + n * 16 + lr;
      #pragma unroll
      for (int j = 0; j < 4; ++j) {
        int row = rb0 + m * 16 + j;
        float v = acc[m][n][j];
        size_t idx = (size_t)row * ldc + col;
        if constexpr (EPI == 1) {
          Cf[idx] = v;
        } else if constexpr (EPI == 2) {
          Ch[idx] = f2bf(v + bf2f(R[idx]));
        } else {
          Ch[idx] = f2bf(v);
        }
      }
    }
  }
}

// ---------------- fallback sentinel ----------------
__global__ void fill_kernel(float* out, int n, float v) {
  int i = blockIdx.x * blockDim.x + threadIdx.x;
  for (; i < n; i += gridDim.x * blockDim.x) out[i] = v;
}

extern "C" void kernel_launch(void* const* d_in, const int* in_sizes, int n_in,
                              void* d_out, int out_size, void* d_ws, size_t ws_size,
                              hipStream_t stream) {
  const float* x  = (const float*)d_in[0];
  const float* W1 = (const float*)d_in[1];
  const float* W2 = (const float*)d_in[2];
  const float* W3 = (const float*)d_in[3];
  float* out = (float*)d_out;

  char* ws = (char*)d_ws;
  size_t off = 0;
  auto alloc = [&](size_t bytes) -> char* {
    char* p = ws + off;
    off += (bytes + 255) & ~(size_t)255;
    return p;
  };

  // ---- persistent buffers (~81MB) ----
  unsigned short* zb  = (unsigned short*)alloc((size_t)MROWS * PDIM * 2);      // 16MB
  unsigned short* kvb = (unsigned short*)alloc((size_t)MROWS * 2 * PDIM * 2);  // 32MB
  unsigned short* vt  = (unsigned short*)alloc((size_t)BATCH * PDIM * L_SEQ * 2); // 16MB
  unsigned short* ar  = (unsigned short*)alloc((size_t)MROWS * PDIM * 2);      // 16MB
  unsigned short* w3b = (unsigned short*)alloc((size_t)DOUT * PDIM * 2);       // 1MB
  size_t persist = off;

  // ---- transient scratch region: converts first, then scores/probs ----
  char* scratch = ws + persist;
  size_t avail = (ws_size > persist) ? (ws_size - persist) : 0;

  size_t xbB  = ((size_t)MROWS * DIN * 2 + 255) & ~(size_t)255;   // 32MB
  size_t w1B  = ((size_t)PDIM * DIN * 2 + 255) & ~(size_t)255;    // 1MB
  size_t w2B  = ((size_t)2 * PDIM * PDIM * 2 + 255) & ~(size_t)255; // 2MB
  size_t convNeed = xbB + w1B + w2B;                              // ~35MB

  size_t scores1 = ((size_t)L_SEQ * L_SEQ * 4 + 255) & ~(size_t)255; // 16MB
  size_t probs1  = ((size_t)L_SEQ * L_SEQ * 2 + 255) & ~(size_t)255; // 8MB
  size_t per = scores1 + probs1;                                  // ~24MB

  if (avail < convNeed || avail < per) {
    float sentinel = 1.0e6f + (float)(ws_size >> 20);
    fill_kernel<<<512, 256, 0, stream>>>(out, out_size, sentinel);
    return;
  }

  // chunking: c batches of attention scratch at a time, balanced chunks
  int c = (int)(avail / per);
  if (c > BATCH) c = BATCH;
  int nch = (BATCH + c - 1) / c;
  c = (BATCH + nch - 1) / nch;   // balance (e.g. 7 -> 4,4)

  unsigned short* xb  = (unsigned short*)(scratch);
  unsigned short* w1b = (unsigned short*)(scratch + xbB);
  unsigned short* w2b = (unsigned short*)(scratch + xbB + w1B);
  // scores/probs overlap the convert buffers (consumed by the time QK^T runs)
  float* scores        = (float*)(scratch);
  unsigned short* probs = (unsigned short*)(scratch + (size_t)c * scores1);

  const float scaling = 0.04419417382415922f;  // 512^-0.5

  // converts
  convert_f32_bf16<<<2048, 256, 0, stream>>>(x,  xb,  (MROWS * DIN) / 4);
  convert_f32_bf16<<<512,  256, 0, stream>>>(W1, w1b, (PDIM * DIN) / 4);
  convert_f32_bf16<<<512,  256, 0, stream>>>(W2, w2b, (2 * PDIM * PDIM) / 4);
  convert_f32_bf16<<<512,  256, 0, stream>>>(W3, w3b, (DOUT * PDIM) / 4);

  // GEMM1: z = x @ W1^T   [16384,1024]x[512,1024] -> [16384,512] bf16
  gemm_bt<0><<<dim3(PDIM / BN, MROWS / BM, 1), 256, 0, stream>>>(
      xb, w1b, zb, zb, MROWS, PDIM, DIN, DIN, DIN, PDIM, 0, 0, 0, 0, 0, 0);

  // GEMM2: kv = z @ W2^T  [16384,512]x[1024,512] -> [16384,1024] bf16
  gemm_bt<0><<<dim3(2 * PDIM / BN, MROWS / BM, 1), 256, 0, stream>>>(
      zb, w2b, kvb, zb, MROWS, 2 * PDIM, PDIM, PDIM, PDIM, 2 * PDIM, 0, 0, 0, 0, 0, 0);

  // V transpose per batch: vt[b][p][l]
  transpose_v_kernel<<<dim3(L_SEQ / 32, PDIM / 32, BATCH), dim3(32, 8), 0, stream>>>(kvb, vt);

  // ---- chunked attention: cb batches per pass via grid.z ----
  for (int b0 = 0; b0 < BATCH; b0 += c) {
    int cb = (BATCH - b0 < c) ? (BATCH - b0) : c;

    // scores[z] = Q_{b0+z} @ K_{b0+z}^T (fp32), causal tile skip
    gemm_bt<1><<<dim3(L_SEQ / BN, L_SEQ / BM, cb), 256, 0, stream>>>(
        zb + (size_t)b0 * PDIM, kvb + (size_t)b0 * 2 * PDIM, scores, zb,
        L_SEQ, L_SEQ, PDIM, BATCH * PDIM, BATCH * 2 * PDIM, L_SEQ,
        (size_t)PDIM, (size_t)2 * PDIM, (size_t)L_SEQ * L_SEQ, 0, 1, 0);

    softmax_causal<<<dim3(L_SEQ, 1, cb), 256, 0, stream>>>(
        scores, probs, (size_t)L_SEQ * L_SEQ, (size_t)L_SEQ * L_SEQ, scaling);

    // attn_out + residual -> ar (bf16), causal K-limit
    gemm_bt<2><<<dim3(PDIM / BN, L_SEQ / BM, cb), 256, 0, stream>>>(
        probs, vt + (size_t)b0 * PDIM * L_SEQ, ar + (size_t)b0 * PDIM,
        zb + (size_t)b0 * PDIM,
        L_SEQ, PDIM, L_SEQ, L_SEQ, L_SEQ, BATCH * PDIM,
        (size_t)L_SEQ * L_SEQ, (size_t)PDIM * L_SEQ, (size_t)PDIM, (size_t)PDIM, 0, 1);
  }

  // GEMM3: out = (attn + residual) @ W3^T -> fp32 d_out
  gemm_bt<1><<<dim3(DOUT / BN, MROWS / BM, 1), 256, 0, stream>>>(
      ar, w3b, out, zb, MROWS, DOUT, PDIM, PDIM, PDIM, DOUT, 0, 0, 0, 0, 0, 0);
}

// Round 4
// 305.151 us; speedup vs baseline: 2.0769x; 1.0532x over previous
//
#include <hip/hip_runtime.h>
#include <cstdint>
#include <cstddef>

#define L_SEQ 2048
#define BATCH 8
#define DIN   1024
#define PDIM  512
#define DOUT  1024
#define MROWS (L_SEQ * BATCH)   // 16384

typedef __attribute__((ext_vector_type(4))) float f32x4;
typedef __attribute__((ext_vector_type(8))) short bf16x8;

__device__ __forceinline__ unsigned short f2bf(float f) {
  union { float f; unsigned int u; } v; v.f = f;
  unsigned int u = v.u;
  unsigned int r = (u + 0x7FFFu + ((u >> 16) & 1u)) >> 16;
  return (unsigned short)r;
}
__device__ __forceinline__ float bf2f(unsigned short h) {
  union { unsigned int u; float f; } v; v.u = ((unsigned int)h) << 16;
  return v.f;
}

// async global->LDS, 16 bytes per lane; dest is wave-uniform base + lane*16
__device__ __forceinline__ void gld16(const unsigned short* g, unsigned short* l) {
  __builtin_amdgcn_global_load_lds(
      (const __attribute__((address_space(1))) void*)g,
      (__attribute__((address_space(3))) void*)l,
      16, 0, 0);
}

// ---------------- fp32 -> bf16 convert (vectorized) ----------------
__global__ void convert_f32_bf16(const float* __restrict__ in,
                                 unsigned short* __restrict__ out, int n4) {
  int i = blockIdx.x * blockDim.x + threadIdx.x;
  int stride = gridDim.x * blockDim.x;
  for (; i < n4; i += stride) {
    float4 v = reinterpret_cast<const float4*>(in)[i];
    ushort4 o;
    o.x = f2bf(v.x); o.y = f2bf(v.y); o.z = f2bf(v.z); o.w = f2bf(v.w);
    reinterpret_cast<ushort4*>(out)[i] = o;
  }
}

// ---------------- V transpose: kv[l][b][512+p] -> vt[b][p][l] ----------------
__global__ void transpose_v_kernel(const unsigned short* __restrict__ kv,
                                   unsigned short* __restrict__ vt) {
  __shared__ unsigned short tile[32][33];
  int b = blockIdx.z;
  int l0 = blockIdx.x * 32;
  int p0 = blockIdx.y * 32;
  const unsigned short* src = kv + (size_t)b * (2 * PDIM) + PDIM;
  unsigned short* dst = vt + (size_t)b * PDIM * L_SEQ;
  int tx = threadIdx.x, ty = threadIdx.y;
  #pragma unroll
  for (int r = ty; r < 32; r += 8)
    tile[r][tx] = src[(size_t)(l0 + r) * (BATCH * 2 * PDIM) + p0 + tx];
  __syncthreads();
  #pragma unroll
  for (int r = ty; r < 32; r += 8)
    dst[(size_t)(p0 + r) * L_SEQ + l0 + tx] = tile[tx][r];
}

// ---------------- row softmax with causal mask ----------------
__global__ void softmax_causal(const float* __restrict__ S,
                               unsigned short* __restrict__ P,
                               size_t sStrideB, size_t pStrideB, float scale) {
  __shared__ float buf[L_SEQ];
  __shared__ float red[4];
  int b = blockIdx.z;
  int i = blockIdx.x;                       // causal row index
  const float* srow = S + b * sStrideB + (size_t)i * L_SEQ;
  unsigned short* prow = P + b * pStrideB + (size_t)i * L_SEQ;
  int t = threadIdx.x;
  int lane = t & 63, wid = t >> 6;

  float lmax = -3.0e38f;
  for (int j = t; j <= i; j += 256) {
    float v = srow[j] * scale;
    buf[j] = v;
    lmax = fmaxf(lmax, v);
  }
  #pragma unroll
  for (int o = 32; o > 0; o >>= 1) lmax = fmaxf(lmax, __shfl_xor(lmax, o));
  if (lane == 0) red[wid] = lmax;
  __syncthreads();
  float m = fmaxf(fmaxf(red[0], red[1]), fmaxf(red[2], red[3]));

  float lsum = 0.0f;
  for (int j = t; j <= i; j += 256) {
    float e = __expf(buf[j] - m);
    buf[j] = e;
    lsum += e;
  }
  #pragma unroll
  for (int o = 32; o > 0; o >>= 1) lsum += __shfl_xor(lsum, o);
  __syncthreads();
  if (lane == 0) red[wid] = lsum;
  __syncthreads();
  float inv = 1.0f / (red[0] + red[1] + red[2] + red[3]);

  // PV's causal K-limit only ever reads up to the next 128-aligned boundary
  int jmax = ((i >> 7) + 1) << 7;
  for (int j = t; j < jmax; j += 256)
    prow[j] = (j <= i) ? f2bf(buf[j] * inv) : (unsigned short)0;
}

// ---------------- bf16 MFMA GEMM: C[M,N] = A[M,K] @ B[N,K]^T ----------------
// 2-phase double-buffered LDS (counted vmcnt, raw barriers).
// EPI: 0 = store bf16, 1 = store fp32, 2 = store bf16 with residual add (R)
// mode: 0 = plain; 1 = causal-triangular tile enumeration via blockIdx.x
//       (QK^T: tn <= tm only); 2 = causal-paired rows (PV: block y handles
//       row-tiles y and NT-1-y sequentially; K limited to tm+BM).
#define BM 128
#define BK 64

template<int EPI, int TBN>
__global__ __launch_bounds__(256)
void gemm_bt(const unsigned short* __restrict__ A,
             const unsigned short* __restrict__ B,
             void* __restrict__ C,
             const unsigned short* __restrict__ R,
             int M, int N, int K, int lda, int ldb, int ldc,
             size_t sAb, size_t sBb, size_t sCb, size_t sRb,
             int mode) {
  constexpr int MF   = (TBN == 128) ? 4 : 2;   // M fragments per wave
  constexpr int BITS = TBN / 32;               // B staging iterations (4 or 2)

  int bz = blockIdx.z;
  A += (size_t)bz * sAb;
  B += (size_t)bz * sBb;
  R += (size_t)bz * sRb;
  float* Cf = (float*)C + (size_t)bz * sCb;
  unsigned short* Ch = (unsigned short*)C + (size_t)bz * sCb;

  __shared__ unsigned short As[2][BM * BK];
  __shared__ unsigned short Bs[2][TBN * BK];

  int t = threadIdx.x;
  int lane = t & 63;
  int wid = t >> 6;
  int wr = (TBN == 128) ? (wid >> 1) * 64 : wid * 32;
  int wc = (TBN == 128) ? (wid & 1) * 64 : 0;
  int lr = lane & 15;
  int kof = (lane >> 4) * 8;
  int srow = lane >> 3;          // staging: 0..7 row within 8-row group
  int scol = (lane & 7) * 8;     // staging: col, 8 bf16 = 16B per lane

  int npass = (mode == 2) ? 2 : 1;

  for (int pass = 0; pass < npass; ++pass) {
    int tmTile, tnBase;
    if (mode == 1) {
      int t3 = blockIdx.x;                    // linear lower-tri index
      int tm3 = 0;
      while ((tm3 + 1) * (tm3 + 2) / 2 <= t3) tm3++;
      tmTile = tm3;
      tnBase = (t3 - tm3 * (tm3 + 1) / 2) * TBN;
    } else if (mode == 2) {
      int nt = M / BM;
      int y = blockIdx.y;
      tmTile = pass ? (nt - 1 - y) : y;
      tnBase = blockIdx.x * TBN;
    } else {
      tmTile = blockIdx.y;
      tnBase = blockIdx.x * TBN;
    }
    int tm = tmTile * BM;
    int kEnd = (mode == 2) ? ((tm + BM) < K ? (tm + BM) : K) : K;
    int nk = kEnd / BK;

    f32x4 acc[MF][4];
    f32x4 zero = {0.0f, 0.0f, 0.0f, 0.0f};
    #pragma unroll
    for (int m = 0; m < MF; ++m)
      #pragma unroll
      for (int n = 0; n < 4; ++n) acc[m][n] = zero;

    // stage K-step `kk` into buffer bi
    auto stage = [&](int bi, int ks) {
      int k0 = ks * BK;
      #pragma unroll
      for (int it = 0; it < 4; ++it) {
        int r = wid * 32 + it * 8;
        gld16(A + (size_t)(tm + r + srow) * lda + k0 + scol, &As[bi][r * BK]);
      }
      #pragma unroll
      for (int it = 0; it < BITS; ++it) {
        int r = wid * (TBN / 4) + it * 8;
        gld16(B + (size_t)(tnBase + r + srow) * ldb + k0 + scol, &Bs[bi][r * BK]);
      }
    };

    stage(0, 0);
    for (int ks = 0; ks < nk; ++ks) {
      int bi = ks & 1;
      if (ks + 1 < nk) {
        stage(bi ^ 1, ks + 1);
        // current buffer's loads done; next (4+BITS) stay in flight
        if constexpr (TBN == 128)
          asm volatile("s_waitcnt vmcnt(8)" ::: "memory");
        else
          asm volatile("s_waitcnt vmcnt(6)" ::: "memory");
      } else {
        asm volatile("s_waitcnt vmcnt(0)" ::: "memory");
      }
      __builtin_amdgcn_s_barrier();
      __builtin_amdgcn_sched_barrier(0);

      #pragma unroll
      for (int kk = 0; kk < BK; kk += 32) {
        bf16x8 af[MF], bfr[4];
        #pragma unroll
        for (int m = 0; m < MF; ++m)
          af[m] = *(const bf16x8*)&As[bi][(wr + m * 16 + lr) * BK + kk + kof];
        #pragma unroll
        for (int n = 0; n < 4; ++n)
          bfr[n] = *(const bf16x8*)&Bs[bi][(wc + n * 16 + lr) * BK + kk + kof];
        #pragma unroll
        for (int m = 0; m < MF; ++m)
          #pragma unroll
          for (int n = 0; n < 4; ++n)
            acc[m][n] = __builtin_amdgcn_mfma_f32_16x16x32_bf16(af[m], bfr[n], acc[m][n], 0, 0, 0);
      }
      asm volatile("" ::: "memory");
      __builtin_amdgcn_s_barrier();
      __builtin_amdgcn_sched_barrier(0);
    }

    int rb0 = tm + wr + (lane >> 4) * 4;     // C/D: col=lane&15, row=(lane>>4)*4+j
    #pragma unroll
    for (int m = 0; m < MF; ++m) {
      #pragma unroll
      for (int n = 0; n < 4; ++n) {
        int col = tnBase + wc + n * 16 + lr;
        #pragma unroll
        for (int j = 0; j < 4; ++j) {
          int row = rb0 + m * 16 + j;
          float v = acc[m][n][j];
          size_t idx = (size_t)row * ldc + col;
          if constexpr (EPI == 1) {
            Cf[idx] = v;
          } else if constexpr (EPI == 2) {
            Ch[idx] = f2bf(v + bf2f(R[idx]));
          } else {
            Ch[idx] = f2bf(v);
          }
        }
      }
    }
  }
}

// ---------------- fallback sentinel ----------------
__global__ void fill_kernel(float* out, int n, float v) {
  int i = blockIdx.x * blockDim.x + threadIdx.x;
  for (; i < n; i += gridDim.x * blockDim.x) out[i] = v;
}

extern "C" void kernel_launch(void* const* d_in, const int* in_sizes, int n_in,
                              void* d_out, int out_size, void* d_ws, size_t ws_size,
                              hipStream_t stream) {
  const float* x  = (const float*)d_in[0];
  const float* W1 = (const float*)d_in[1];
  const float* W2 = (const float*)d_in[2];
  const float* W3 = (const float*)d_in[3];
  float* out = (float*)d_out;

  char* ws = (char*)d_ws;
  size_t off = 0;
  auto alloc = [&](size_t bytes) -> char* {
    char* p = ws + off;
    off += (bytes + 255) & ~(size_t)255;
    return p;
  };

  // ---- persistent buffers (~81MB) ----
  unsigned short* zb  = (unsigned short*)alloc((size_t)MROWS * PDIM * 2);      // 16MB
  unsigned short* kvb = (unsigned short*)alloc((size_t)MROWS * 2 * PDIM * 2);  // 32MB
  unsigned short* vt  = (unsigned short*)alloc((size_t)BATCH * PDIM * L_SEQ * 2); // 16MB
  unsigned short* ar  = (unsigned short*)alloc((size_t)MROWS * PDIM * 2);      // 16MB
  unsigned short* w3b = (unsigned short*)alloc((size_t)DOUT * PDIM * 2);       // 1MB
  size_t persist = off;

  // ---- transient scratch region: converts first, then scores/probs ----
  char* scratch = ws + persist;
  size_t avail = (ws_size > persist) ? (ws_size - persist) : 0;

  size_t xbB  = ((size_t)MROWS * DIN * 2 + 255) & ~(size_t)255;   // 32MB
  size_t w1B  = ((size_t)PDIM * DIN * 2 + 255) & ~(size_t)255;    // 1MB
  size_t w2B  = ((size_t)2 * PDIM * PDIM * 2 + 255) & ~(size_t)255; // 2MB
  size_t convNeed = xbB + w1B + w2B;                              // ~35MB

  size_t scores1 = ((size_t)L_SEQ * L_SEQ * 4 + 255) & ~(size_t)255; // 16MB
  size_t probs1  = ((size_t)L_SEQ * L_SEQ * 2 + 255) & ~(size_t)255; // 8MB
  size_t per = scores1 + probs1;                                  // ~24MB

  if (avail < convNeed || avail < per) {
    float sentinel = 1.0e6f + (float)(ws_size >> 20);
    fill_kernel<<<512, 256, 0, stream>>>(out, out_size, sentinel);
    return;
  }

  // chunking: c batches of attention scratch at a time, balanced chunks
  int c = (int)(avail / per);
  if (c > BATCH) c = BATCH;
  int nch = (BATCH + c - 1) / c;
  c = (BATCH + nch - 1) / nch;   // balance (e.g. 7 -> 4,4)

  unsigned short* xb  = (unsigned short*)(scratch);
  unsigned short* w1b = (unsigned short*)(scratch + xbB);
  unsigned short* w2b = (unsigned short*)(scratch + xbB + w1B);
  // scores/probs overlap the convert buffers (consumed by the time QK^T runs)
  float* scores        = (float*)(scratch);
  unsigned short* probs = (unsigned short*)(scratch + (size_t)c * scores1);

  const float scaling = 0.04419417382415922f;  // 512^-0.5
  const int NTRI = (L_SEQ / BM) * (L_SEQ / BM + 1) / 2;   // 136 lower-tri tiles

  // converts
  convert_f32_bf16<<<2048, 256, 0, stream>>>(x,  xb,  (MROWS * DIN) / 4);
  convert_f32_bf16<<<512,  256, 0, stream>>>(W1, w1b, (PDIM * DIN) / 4);
  convert_f32_bf16<<<512,  256, 0, stream>>>(W2, w2b, (2 * PDIM * PDIM) / 4);
  convert_f32_bf16<<<512,  256, 0, stream>>>(W3, w3b, (DOUT * PDIM) / 4);

  // GEMM1: z = x @ W1^T   [16384,1024]x[512,1024] -> [16384,512] bf16
  gemm_bt<0, 128><<<dim3(PDIM / 128, MROWS / BM, 1), 256, 0, stream>>>(
      xb, w1b, zb, zb, MROWS, PDIM, DIN, DIN, DIN, PDIM, 0, 0, 0, 0, 0);

  // GEMM2: kv = z @ W2^T  [16384,512]x[1024,512] -> [16384,1024] bf16
  gemm_bt<0, 128><<<dim3(2 * PDIM / 128, MROWS / BM, 1), 256, 0, stream>>>(
      zb, w2b, kvb, zb, MROWS, 2 * PDIM, PDIM, PDIM, PDIM, 2 * PDIM, 0, 0, 0, 0, 0);

  // V transpose per batch: vt[b][p][l]
  transpose_v_kernel<<<dim3(L_SEQ / 32, PDIM / 32, BATCH), dim3(32, 8), 0, stream>>>(kvb, vt);

  // ---- chunked attention: cb batches per pass via grid.z ----
  for (int b0 = 0; b0 < BATCH; b0 += c) {
    int cb = (BATCH - b0 < c) ? (BATCH - b0) : c;

    // scores[z] = Q @ K^T (fp32), triangular tile enumeration (mode 1)
    gemm_bt<1, 128><<<dim3(NTRI, 1, cb), 256, 0, stream>>>(
        zb + (size_t)b0 * PDIM, kvb + (size_t)b0 * 2 * PDIM, scores, zb,
        L_SEQ, L_SEQ, PDIM, BATCH * PDIM, BATCH * 2 * PDIM, L_SEQ,
        (size_t)PDIM, (size_t)2 * PDIM, (size_t)L_SEQ * L_SEQ, 0, 1);

    softmax_causal<<<dim3(L_SEQ, 1, cb), 256, 0, stream>>>(
        scores, probs, (size_t)L_SEQ * L_SEQ, (size_t)L_SEQ * L_SEQ, scaling);

    // attn_out + residual -> ar (bf16), causal-paired rows (mode 2), BN=64
    gemm_bt<2, 64><<<dim3(PDIM / 64, L_SEQ / BM / 2, cb), 256, 0, stream>>>(
        probs, vt + (size_t)b0 * PDIM * L_SEQ, ar + (size_t)b0 * PDIM,
        zb + (size_t)b0 * PDIM,
        L_SEQ, PDIM, L_SEQ, L_SEQ, L_SEQ, BATCH * PDIM,
        (size_t)L_SEQ * L_SEQ, (size_t)PDIM * L_SEQ, (size_t)PDIM, (size_t)PDIM, 2);
  }

  // GEMM3: out = (attn + residual) @ W3^T -> fp32 d_out
  gemm_bt<1, 128><<<dim3(DOUT / 128, MROWS / BM, 1), 256, 0, stream>>>(
      ar, w3b, out, zb, MROWS, DOUT, PDIM, PDIM, PDIM, DOUT, 0, 0, 0, 0, 0);
}

// Round 5
// 229.306 us; speedup vs baseline: 2.7639x; 1.3308x over previous
//
#include <hip/hip_runtime.h>
#include <cstdint>
#include <cstddef>

#define L_SEQ 2048
#define BATCH 8
#define DIN   1024
#define PDIM  512
#define DOUT  1024
#define MROWS (L_SEQ * BATCH)   // 16384

typedef __attribute__((ext_vector_type(4))) float f32x4;
typedef __attribute__((ext_vector_type(8))) short bf16x8;

__device__ __forceinline__ unsigned short f2bf(float f) {
  union { float f; unsigned int u; } v; v.f = f;
  unsigned int u = v.u;
  unsigned int r = (u + 0x7FFFu + ((u >> 16) & 1u)) >> 16;
  return (unsigned short)r;
}
__device__ __forceinline__ float bf2f(unsigned short h) {
  union { unsigned int u; float f; } v; v.u = ((unsigned int)h) << 16;
  return v.f;
}

// async global->LDS, 16 bytes per lane; dest is wave-uniform base + lane*16
__device__ __forceinline__ void gld16(const unsigned short* g, unsigned short* l) {
  __builtin_amdgcn_global_load_lds(
      (const __attribute__((address_space(1))) void*)g,
      (__attribute__((address_space(3))) void*)l,
      16, 0, 0);
}

// T1: bijective XCD-chunked block remap (m204). HW assigns consecutive linear
// block ids round-robin across 8 XCDs; remap so each XCD gets a contiguous
// chunk of logical work -> panel reuse stays within one XCD's L2.
__device__ __forceinline__ int swz_lin(int lin, int nwg) {
  int q = nwg >> 3, r = nwg & 7;
  int xcd = lin & 7;
  int base = (xcd < r) ? xcd * (q + 1) : r * (q + 1) + (xcd - r) * q;
  return base + (lin >> 3);
}

// ---------------- fp32 -> bf16 convert (vectorized) ----------------
__global__ void convert_f32_bf16(const float* __restrict__ in,
                                 unsigned short* __restrict__ out, int n4) {
  int i = blockIdx.x * blockDim.x + threadIdx.x;
  int stride = gridDim.x * blockDim.x;
  for (; i < n4; i += stride) {
    float4 v = reinterpret_cast<const float4*>(in)[i];
    ushort4 o;
    o.x = f2bf(v.x); o.y = f2bf(v.y); o.z = f2bf(v.z); o.w = f2bf(v.w);
    reinterpret_cast<ushort4*>(out)[i] = o;
  }
}

// ---------------- V transpose: kv[l][b][512+p] -> vt[b][p][l] ----------------
__global__ void transpose_v_kernel(const unsigned short* __restrict__ kv,
                                   unsigned short* __restrict__ vt) {
  __shared__ unsigned short tile[32][33];
  int b = blockIdx.z;
  int l0 = blockIdx.x * 32;
  int p0 = blockIdx.y * 32;
  const unsigned short* src = kv + (size_t)b * (2 * PDIM) + PDIM;
  unsigned short* dst = vt + (size_t)b * PDIM * L_SEQ;
  int tx = threadIdx.x, ty = threadIdx.y;
  #pragma unroll
  for (int r = ty; r < 32; r += 8)
    tile[r][tx] = src[(size_t)(l0 + r) * (BATCH * 2 * PDIM) + p0 + tx];
  __syncthreads();
  #pragma unroll
  for (int r = ty; r < 32; r += 8)
    dst[(size_t)(p0 + r) * L_SEQ + l0 + tx] = tile[tx][r];
}

// ---------------- row softmax with causal mask (IN-PLACE probs) -------------
// probs (bf16) overwrite the first half of each score row's bytes. All score
// reads happen before the barrier; writes after -> row-local in-place is safe.
__global__ void softmax_causal(const float* __restrict__ S,
                               unsigned short* __restrict__ P,
                               size_t sStrideB, size_t pStrideB, float scale) {
  __shared__ float buf[L_SEQ];
  __shared__ float red[4];
  int b = blockIdx.z;
  int i = blockIdx.x;                       // causal row index
  const float* srow = S + b * sStrideB + (size_t)i * L_SEQ;
  unsigned short* prow = P + b * pStrideB + (size_t)i * (2 * L_SEQ);
  int t = threadIdx.x;
  int lane = t & 63, wid = t >> 6;

  float lmax = -3.0e38f;
  for (int j = t; j <= i; j += 256) {
    float v = srow[j] * scale;
    buf[j] = v;
    lmax = fmaxf(lmax, v);
  }
  #pragma unroll
  for (int o = 32; o > 0; o >>= 1) lmax = fmaxf(lmax, __shfl_xor(lmax, o));
  if (lane == 0) red[wid] = lmax;
  __syncthreads();
  float m = fmaxf(fmaxf(red[0], red[1]), fmaxf(red[2], red[3]));

  float lsum = 0.0f;
  for (int j = t; j <= i; j += 256) {
    float e = __expf(buf[j] - m);
    buf[j] = e;
    lsum += e;
  }
  #pragma unroll
  for (int o = 32; o > 0; o >>= 1) lsum += __shfl_xor(lsum, o);
  __syncthreads();
  if (lane == 0) red[wid] = lsum;
  __syncthreads();
  float inv = 1.0f / (red[0] + red[1] + red[2] + red[3]);

  // PV's causal K-limit only reads up to the next 128-aligned boundary
  int jmax = ((i >> 7) + 1) << 7;
  for (int j = t; j < jmax; j += 256)
    prow[j] = (j <= i) ? f2bf(buf[j] * inv) : (unsigned short)0;
}

// ---------------- bf16 MFMA GEMM: C[M,N] = A[M,K] @ B[N,K]^T ----------------
// 2-phase double-buffered LDS (counted vmcnt, raw barriers) + T1 XCD swizzle.
// EPI: 0 = store bf16, 1 = store fp32, 2 = store bf16 with residual add (R)
// mode: 0 = plain; 1 = causal lower-triangular tile enumeration (QK^T);
//       2 = causal-paired row-tiles (PV: block y does rows y and NT-1-y).
#define BM 128
#define BK 64

template<int EPI, int TBN>
__global__ __launch_bounds__(256)
void gemm_bt(const unsigned short* __restrict__ A,
             const unsigned short* __restrict__ B,
             void* __restrict__ C,
             const unsigned short* __restrict__ R,
             int M, int N, int K, int lda, int ldb, int ldc,
             size_t sAb, size_t sBb, size_t sCb, size_t sRb,
             int mode) {
  constexpr int MF   = (TBN == 128) ? 4 : 2;   // M fragments per wave
  constexpr int BITS = TBN / 32;               // B staging iterations (4 or 2)

  // T1 swizzle + decode
  int gx = gridDim.x, gy = gridDim.y;
  int nwg = gx * gy * (int)gridDim.z;
  int lin = ((int)blockIdx.z * gy + (int)blockIdx.y) * gx + (int)blockIdx.x;
  int wg = swz_lin(lin, nwg);
  int bx = wg % gx;
  int rem = wg / gx;
  int by = rem % gy;
  int bz = rem / gy;

  A += (size_t)bz * sAb;
  B += (size_t)bz * sBb;
  R += (size_t)bz * sRb;
  float* Cf = (float*)C + (size_t)bz * sCb;
  unsigned short* Ch = (unsigned short*)C + (size_t)bz * sCb;

  __shared__ unsigned short As[2][BM * BK];
  __shared__ unsigned short Bs[2][TBN * BK];

  int t = threadIdx.x;
  int lane = t & 63;
  int wid = t >> 6;
  int wr = (TBN == 128) ? (wid >> 1) * 64 : wid * 32;
  int wc = (TBN == 128) ? (wid & 1) * 64 : 0;
  int lr = lane & 15;
  int kof = (lane >> 4) * 8;
  int srow = lane >> 3;          // staging: 0..7 row within 8-row group
  int scol = (lane & 7) * 8;     // staging: col, 8 bf16 = 16B per lane

  int npass = (mode == 2) ? 2 : 1;

  for (int pass = 0; pass < npass; ++pass) {
    int tmTile, tnBase;
    if (mode == 1) {
      int t3 = bx;                            // linear lower-tri index
      int tm3 = 0;
      while ((tm3 + 1) * (tm3 + 2) / 2 <= t3) tm3++;
      tmTile = tm3;
      tnBase = (t3 - tm3 * (tm3 + 1) / 2) * TBN;
    } else if (mode == 2) {
      int nt = M / BM;
      tmTile = pass ? (nt - 1 - by) : by;
      tnBase = bx * TBN;
    } else {
      tmTile = by;
      tnBase = bx * TBN;
    }
    int tm = tmTile * BM;
    int kEnd = (mode == 2) ? ((tm + BM) < K ? (tm + BM) : K) : K;
    int nk = kEnd / BK;

    f32x4 acc[MF][4];
    f32x4 zero = {0.0f, 0.0f, 0.0f, 0.0f};
    #pragma unroll
    for (int m = 0; m < MF; ++m)
      #pragma unroll
      for (int n = 0; n < 4; ++n) acc[m][n] = zero;

    // stage K-step `ks` into buffer bi
    auto stage = [&](int bi, int ks) {
      int k0 = ks * BK;
      #pragma unroll
      for (int it = 0; it < 4; ++it) {
        int r = wid * 32 + it * 8;
        gld16(A + (size_t)(tm + r + srow) * lda + k0 + scol, &As[bi][r * BK]);
      }
      #pragma unroll
      for (int it = 0; it < BITS; ++it) {
        int r = wid * (TBN / 4) + it * 8;
        gld16(B + (size_t)(tnBase + r + srow) * ldb + k0 + scol, &Bs[bi][r * BK]);
      }
    };

    stage(0, 0);
    for (int ks = 0; ks < nk; ++ks) {
      int bi = ks & 1;
      if (ks + 1 < nk) {
        stage(bi ^ 1, ks + 1);
        // current buffer's loads done; next (4+BITS) stay in flight
        if constexpr (TBN == 128)
          asm volatile("s_waitcnt vmcnt(8)" ::: "memory");
        else
          asm volatile("s_waitcnt vmcnt(6)" ::: "memory");
      } else {
        asm volatile("s_waitcnt vmcnt(0)" ::: "memory");
      }
      __builtin_amdgcn_s_barrier();
      __builtin_amdgcn_sched_barrier(0);

      #pragma unroll
      for (int kk = 0; kk < BK; kk += 32) {
        bf16x8 af[MF], bfr[4];
        #pragma unroll
        for (int m = 0; m < MF; ++m)
          af[m] = *(const bf16x8*)&As[bi][(wr + m * 16 + lr) * BK + kk + kof];
        #pragma unroll
        for (int n = 0; n < 4; ++n)
          bfr[n] = *(const bf16x8*)&Bs[bi][(wc + n * 16 + lr) * BK + kk + kof];
        #pragma unroll
        for (int m = 0; m < MF; ++m)
          #pragma unroll
          for (int n = 0; n < 4; ++n)
            acc[m][n] = __builtin_amdgcn_mfma_f32_16x16x32_bf16(af[m], bfr[n], acc[m][n], 0, 0, 0);
      }
      asm volatile("" ::: "memory");
      __builtin_amdgcn_s_barrier();
      __builtin_amdgcn_sched_barrier(0);
    }

    int rb0 = tm + wr + (lane >> 4) * 4;     // C/D: col=lane&15, row=(lane>>4)*4+j
    #pragma unroll
    for (int m = 0; m < MF; ++m) {
      #pragma unroll
      for (int n = 0; n < 4; ++n) {
        int col = tnBase + wc + n * 16 + lr;
        #pragma unroll
        for (int j = 0; j < 4; ++j) {
          int row = rb0 + m * 16 + j;
          float v = acc[m][n][j];
          size_t idx = (size_t)row * ldc + col;
          if constexpr (EPI == 1) {
            Cf[idx] = v;
          } else if constexpr (EPI == 2) {
            Ch[idx] = f2bf(v + bf2f(R[idx]));
          } else {
            Ch[idx] = f2bf(v);
          }
        }
      }
    }
  }
}

// ---------------- fallback sentinel ----------------
__global__ void fill_kernel(float* out, int n, float v) {
  int i = blockIdx.x * blockDim.x + threadIdx.x;
  for (; i < n; i += gridDim.x * blockDim.x) out[i] = v;
}

extern "C" void kernel_launch(void* const* d_in, const int* in_sizes, int n_in,
                              void* d_out, int out_size, void* d_ws, size_t ws_size,
                              hipStream_t stream) {
  const float* x  = (const float*)d_in[0];
  const float* W1 = (const float*)d_in[1];
  const float* W2 = (const float*)d_in[2];
  const float* W3 = (const float*)d_in[3];
  float* out = (float*)d_out;

  char* ws = (char*)d_ws;
  size_t off = 0;
  auto alloc = [&](size_t bytes) -> char* {
    char* p = ws + off;
    off += (bytes + 255) & ~(size_t)255;
    return p;
  };

  // ---- persistent buffers (~81MB) ----
  unsigned short* zb  = (unsigned short*)alloc((size_t)MROWS * PDIM * 2);      // 16MB
  unsigned short* kvb = (unsigned short*)alloc((size_t)MROWS * 2 * PDIM * 2);  // 32MB
  unsigned short* vt  = (unsigned short*)alloc((size_t)BATCH * PDIM * L_SEQ * 2); // 16MB
  unsigned short* ar  = (unsigned short*)alloc((size_t)MROWS * PDIM * 2);      // 16MB
  unsigned short* w3b = (unsigned short*)alloc((size_t)DOUT * PDIM * 2);       // 1MB
  size_t persist = off;

  // ---- transient scratch region: converts first, then scores (probs in-place)
  char* scratch = ws + persist;
  size_t avail = (ws_size > persist) ? (ws_size - persist) : 0;

  size_t xbB  = ((size_t)MROWS * DIN * 2 + 255) & ~(size_t)255;   // 32MB
  size_t w1B  = ((size_t)PDIM * DIN * 2 + 255) & ~(size_t)255;    // 1MB
  size_t w2B  = ((size_t)2 * PDIM * PDIM * 2 + 255) & ~(size_t)255; // 2MB
  size_t convNeed = xbB + w1B + w2B;                              // ~35MB

  size_t scores1 = ((size_t)L_SEQ * L_SEQ * 4 + 255) & ~(size_t)255; // 16MB
  size_t per = scores1;                                           // probs in-place

  if (avail < convNeed || avail < per) {
    float sentinel = 1.0e6f + (float)(ws_size >> 20);
    fill_kernel<<<512, 256, 0, stream>>>(out, out_size, sentinel);
    return;
  }

  // chunking: c batches of attention scratch at a time, balanced chunks
  int c = (int)(avail / per);
  if (c > BATCH) c = BATCH;
  int nch = (BATCH + c - 1) / c;
  c = (BATCH + nch - 1) / nch;   // balance (e.g. 6 -> 4,4)

  unsigned short* xb  = (unsigned short*)(scratch);
  unsigned short* w1b = (unsigned short*)(scratch + xbB);
  unsigned short* w2b = (unsigned short*)(scratch + xbB + w1B);
  // scores overlap the convert buffers (consumed by the time QK^T runs);
  // probs live in-place inside the scores rows (bf16 over first half of row)
  float* scores         = (float*)(scratch);
  unsigned short* probs = (unsigned short*)(scratch);

  const float scaling = 0.04419417382415922f;  // 512^-0.5
  const int NTRI = (L_SEQ / BM) * (L_SEQ / BM + 1) / 2;   // 136 lower-tri tiles

  // converts
  convert_f32_bf16<<<2048, 256, 0, stream>>>(x,  xb,  (MROWS * DIN) / 4);
  convert_f32_bf16<<<512,  256, 0, stream>>>(W1, w1b, (PDIM * DIN) / 4);
  convert_f32_bf16<<<512,  256, 0, stream>>>(W2, w2b, (2 * PDIM * PDIM) / 4);
  convert_f32_bf16<<<512,  256, 0, stream>>>(W3, w3b, (DOUT * PDIM) / 4);

  // GEMM1: z = x @ W1^T   [16384,1024]x[512,1024] -> [16384,512] bf16
  gemm_bt<0, 128><<<dim3(PDIM / 128, MROWS / BM, 1), 256, 0, stream>>>(
      xb, w1b, zb, zb, MROWS, PDIM, DIN, DIN, DIN, PDIM, 0, 0, 0, 0, 0);

  // GEMM2: kv = z @ W2^T  [16384,512]x[1024,512] -> [16384,1024] bf16
  gemm_bt<0, 128><<<dim3(2 * PDIM / 128, MROWS / BM, 1), 256, 0, stream>>>(
      zb, w2b, kvb, zb, MROWS, 2 * PDIM, PDIM, PDIM, PDIM, 2 * PDIM, 0, 0, 0, 0, 0);

  // V transpose per batch: vt[b][p][l]
  transpose_v_kernel<<<dim3(L_SEQ / 32, PDIM / 32, BATCH), dim3(32, 8), 0, stream>>>(kvb, vt);

  // ---- chunked attention: cb batches per pass via grid.z ----
  for (int b0 = 0; b0 < BATCH; b0 += c) {
    int cb = (BATCH - b0 < c) ? (BATCH - b0) : c;

    // scores[z] = Q @ K^T (fp32), triangular tile enumeration (mode 1)
    gemm_bt<1, 128><<<dim3(NTRI, 1, cb), 256, 0, stream>>>(
        zb + (size_t)b0 * PDIM, kvb + (size_t)b0 * 2 * PDIM, scores, zb,
        L_SEQ, L_SEQ, PDIM, BATCH * PDIM, BATCH * 2 * PDIM, L_SEQ,
        (size_t)PDIM, (size_t)2 * PDIM, (size_t)L_SEQ * L_SEQ, 0, 1);

    softmax_causal<<<dim3(L_SEQ, 1, cb), 256, 0, stream>>>(
        scores, probs, (size_t)L_SEQ * L_SEQ, (size_t)2 * L_SEQ * L_SEQ, scaling);

    // attn_out + residual -> ar (bf16), causal-paired rows (mode 2), BN=64
    // probs rows have stride 2*L_SEQ shorts (in-place inside fp32 score rows)
    gemm_bt<2, 64><<<dim3(PDIM / 64, L_SEQ / BM / 2, cb), 256, 0, stream>>>(
        probs, vt + (size_t)b0 * PDIM * L_SEQ, ar + (size_t)b0 * PDIM,
        zb + (size_t)b0 * PDIM,
        L_SEQ, PDIM, L_SEQ, 2 * L_SEQ, L_SEQ, BATCH * PDIM,
        (size_t)2 * L_SEQ * L_SEQ, (size_t)PDIM * L_SEQ, (size_t)PDIM, (size_t)PDIM, 2);
  }

  // GEMM3: out = (attn + residual) @ W3^T -> fp32 d_out
  gemm_bt<1, 128><<<dim3(DOUT / 128, MROWS / BM, 1), 256, 0, stream>>>(
      ar, w3b, out, zb, MROWS, DOUT, PDIM, PDIM, PDIM, DOUT, 0, 0, 0, 0, 0);
}

// Round 6
// 224.539 us; speedup vs baseline: 2.8225x; 1.0212x over previous
//
#include <hip/hip_runtime.h>
#include <cstdint>
#include <cstddef>

#define L_SEQ 2048
#define BATCH 8
#define DIN   1024
#define PDIM  512
#define DOUT  1024
#define MROWS (L_SEQ * BATCH)   // 16384

typedef __attribute__((ext_vector_type(4))) float f32x4;
typedef __attribute__((ext_vector_type(8))) short bf16x8;

__device__ __forceinline__ unsigned short f2bf(float f) {
  union { float f; unsigned int u; } v; v.f = f;
  unsigned int u = v.u;
  unsigned int r = (u + 0x7FFFu + ((u >> 16) & 1u)) >> 16;
  return (unsigned short)r;
}
__device__ __forceinline__ float bf2f(unsigned short h) {
  union { unsigned int u; float f; } v; v.u = ((unsigned int)h) << 16;
  return v.f;
}

// async global->LDS, 16 bytes per lane; dest is wave-uniform base + lane*16
__device__ __forceinline__ void gld16(const unsigned short* g, unsigned short* l) {
  __builtin_amdgcn_global_load_lds(
      (const __attribute__((address_space(1))) void*)g,
      (__attribute__((address_space(3))) void*)l,
      16, 0, 0);
}

// T1: bijective XCD-chunked block remap (m204). HW assigns consecutive linear
// block ids round-robin across 8 XCDs; remap so each XCD gets a contiguous
// chunk of logical work -> panel reuse stays within one XCD's L2.
__device__ __forceinline__ int swz_lin(int lin, int nwg) {
  int q = nwg >> 3, r = nwg & 7;
  int xcd = lin & 7;
  int base = (xcd < r) ? xcd * (q + 1) : r * (q + 1) + (xcd - r) * q;
  return base + (lin >> 3);
}

// ---------------- fp32 -> bf16 convert (vectorized) ----------------
__global__ void convert_f32_bf16(const float* __restrict__ in,
                                 unsigned short* __restrict__ out, int n4) {
  int i = blockIdx.x * blockDim.x + threadIdx.x;
  int stride = gridDim.x * blockDim.x;
  for (; i < n4; i += stride) {
    float4 v = reinterpret_cast<const float4*>(in)[i];
    ushort4 o;
    o.x = f2bf(v.x); o.y = f2bf(v.y); o.z = f2bf(v.z); o.w = f2bf(v.w);
    reinterpret_cast<ushort4*>(out)[i] = o;
  }
}

// ---------------- V transpose: kv[l][b][512+p] -> vt[b][p][l] ----------------
__global__ void transpose_v_kernel(const unsigned short* __restrict__ kv,
                                   unsigned short* __restrict__ vt) {
  __shared__ unsigned short tile[32][33];
  int b = blockIdx.z;
  int l0 = blockIdx.x * 32;
  int p0 = blockIdx.y * 32;
  const unsigned short* src = kv + (size_t)b * (2 * PDIM) + PDIM;
  unsigned short* dst = vt + (size_t)b * PDIM * L_SEQ;
  int tx = threadIdx.x, ty = threadIdx.y;
  #pragma unroll
  for (int r = ty; r < 32; r += 8)
    tile[r][tx] = src[(size_t)(l0 + r) * (BATCH * 2 * PDIM) + p0 + tx];
  __syncthreads();
  #pragma unroll
  for (int r = ty; r < 32; r += 8)
    dst[(size_t)(p0 + r) * L_SEQ + l0 + tx] = tile[tx][r];
}

// ---------------- row softmax with causal mask (bf16 in / in-place bf16 out) -
// scores are bf16; probs overwrite the SAME row addresses. All reads happen
// before the write phase -> row-local in-place is safe.
__global__ void softmax_causal(unsigned short* __restrict__ S,
                               size_t strideB, float scale) {
  __shared__ float buf[L_SEQ];
  __shared__ float red[4];
  int b = blockIdx.z;
  int i = blockIdx.x;                       // causal row index
  unsigned short* row = S + b * strideB + (size_t)i * L_SEQ;
  int t = threadIdx.x;
  int lane = t & 63, wid = t >> 6;

  float lmax = -3.0e38f;
  for (int j = t; j <= i; j += 256) {
    float v = bf2f(row[j]) * scale;
    buf[j] = v;
    lmax = fmaxf(lmax, v);
  }
  #pragma unroll
  for (int o = 32; o > 0; o >>= 1) lmax = fmaxf(lmax, __shfl_xor(lmax, o));
  if (lane == 0) red[wid] = lmax;
  __syncthreads();
  float m = fmaxf(fmaxf(red[0], red[1]), fmaxf(red[2], red[3]));

  float lsum = 0.0f;
  for (int j = t; j <= i; j += 256) {
    float e = __expf(buf[j] - m);
    buf[j] = e;
    lsum += e;
  }
  #pragma unroll
  for (int o = 32; o > 0; o >>= 1) lsum += __shfl_xor(lsum, o);
  __syncthreads();
  if (lane == 0) red[wid] = lsum;
  __syncthreads();
  float inv = 1.0f / (red[0] + red[1] + red[2] + red[3]);

  // PV's causal K-limit reads exactly up to the next 128-aligned boundary
  int jmax = ((i >> 7) + 1) << 7;
  for (int j = t; j < jmax; j += 256)
    row[j] = (j <= i) ? f2bf(buf[j] * inv) : (unsigned short)0;
}

// ---------------- bf16 MFMA GEMM: C[M,N] = A[M,K] @ B[N,K]^T ----------------
// 2-phase double-buffered LDS (counted vmcnt, raw barriers) + T1 XCD swizzle.
// EPI: 0 = store bf16, 1 = store fp32, 2 = store bf16 with residual add (R)
// mode: 0 = plain; 1 = causal lower-triangular tile enumeration (QK^T);
//       2 = causal-paired row-tiles (PV: block y does rows y and NT-1-y).
#define BM 128
#define BK 64

template<int EPI, int TBN>
__global__ __launch_bounds__(256)
void gemm_bt(const unsigned short* __restrict__ A,
             const unsigned short* __restrict__ B,
             void* __restrict__ C,
             const unsigned short* __restrict__ R,
             int M, int N, int K, int lda, int ldb, int ldc,
             size_t sAb, size_t sBb, size_t sCb, size_t sRb,
             int mode) {
  constexpr int MF   = (TBN == 128) ? 4 : 2;   // M fragments per wave
  constexpr int BITS = TBN / 32;               // B staging iterations (4 or 2)

  // T1 swizzle + decode
  int gx = gridDim.x, gy = gridDim.y;
  int nwg = gx * gy * (int)gridDim.z;
  int lin = ((int)blockIdx.z * gy + (int)blockIdx.y) * gx + (int)blockIdx.x;
  int wg = swz_lin(lin, nwg);
  int bx = wg % gx;
  int rem = wg / gx;
  int by = rem % gy;
  int bz = rem / gy;

  A += (size_t)bz * sAb;
  B += (size_t)bz * sBb;
  R += (size_t)bz * sRb;
  float* Cf = (float*)C + (size_t)bz * sCb;
  unsigned short* Ch = (unsigned short*)C + (size_t)bz * sCb;

  __shared__ unsigned short As[2][BM * BK];
  __shared__ unsigned short Bs[2][TBN * BK];

  int t = threadIdx.x;
  int lane = t & 63;
  int wid = t >> 6;
  int wr = (TBN == 128) ? (wid >> 1) * 64 : wid * 32;
  int wc = (TBN == 128) ? (wid & 1) * 64 : 0;
  int lr = lane & 15;
  int kof = (lane >> 4) * 8;
  int srow = lane >> 3;          // staging: 0..7 row within 8-row group
  int scol = (lane & 7) * 8;     // staging: col, 8 bf16 = 16B per lane

  int npass = (mode == 2) ? 2 : 1;

  for (int pass = 0; pass < npass; ++pass) {
    int tmTile, tnBase;
    if (mode == 1) {
      int t3 = bx;                            // linear lower-tri index
      int tm3 = 0;
      while ((tm3 + 1) * (tm3 + 2) / 2 <= t3) tm3++;
      tmTile = tm3;
      tnBase = (t3 - tm3 * (tm3 + 1) / 2) * TBN;
    } else if (mode == 2) {
      int nt = M / BM;
      tmTile = pass ? (nt - 1 - by) : by;
      tnBase = bx * TBN;
    } else {
      tmTile = by;
      tnBase = bx * TBN;
    }
    int tm = tmTile * BM;
    int kEnd = (mode == 2) ? ((tm + BM) < K ? (tm + BM) : K) : K;
    int nk = kEnd / BK;

    f32x4 acc[MF][4];
    f32x4 zero = {0.0f, 0.0f, 0.0f, 0.0f};
    #pragma unroll
    for (int m = 0; m < MF; ++m)
      #pragma unroll
      for (int n = 0; n < 4; ++n) acc[m][n] = zero;

    // stage K-step `ks` into buffer bi
    auto stage = [&](int bi, int ks) {
      int k0 = ks * BK;
      #pragma unroll
      for (int it = 0; it < 4; ++it) {
        int r = wid * 32 + it * 8;
        gld16(A + (size_t)(tm + r + srow) * lda + k0 + scol, &As[bi][r * BK]);
      }
      #pragma unroll
      for (int it = 0; it < BITS; ++it) {
        int r = wid * (TBN / 4) + it * 8;
        gld16(B + (size_t)(tnBase + r + srow) * ldb + k0 + scol, &Bs[bi][r * BK]);
      }
    };

    stage(0, 0);
    for (int ks = 0; ks < nk; ++ks) {
      int bi = ks & 1;
      if (ks + 1 < nk) {
        stage(bi ^ 1, ks + 1);
        // current buffer's loads done; next (4+BITS) stay in flight
        if constexpr (TBN == 128)
          asm volatile("s_waitcnt vmcnt(8)" ::: "memory");
        else
          asm volatile("s_waitcnt vmcnt(6)" ::: "memory");
      } else {
        asm volatile("s_waitcnt vmcnt(0)" ::: "memory");
      }
      __builtin_amdgcn_s_barrier();
      __builtin_amdgcn_sched_barrier(0);

      #pragma unroll
      for (int kk = 0; kk < BK; kk += 32) {
        bf16x8 af[MF], bfr[4];
        #pragma unroll
        for (int m = 0; m < MF; ++m)
          af[m] = *(const bf16x8*)&As[bi][(wr + m * 16 + lr) * BK + kk + kof];
        #pragma unroll
        for (int n = 0; n < 4; ++n)
          bfr[n] = *(const bf16x8*)&Bs[bi][(wc + n * 16 + lr) * BK + kk + kof];
        #pragma unroll
        for (int m = 0; m < MF; ++m)
          #pragma unroll
          for (int n = 0; n < 4; ++n)
            acc[m][n] = __builtin_amdgcn_mfma_f32_16x16x32_bf16(af[m], bfr[n], acc[m][n], 0, 0, 0);
      }
      asm volatile("" ::: "memory");
      __builtin_amdgcn_s_barrier();
      __builtin_amdgcn_sched_barrier(0);
    }

    int rb0 = tm + wr + (lane >> 4) * 4;     // C/D: col=lane&15, row=(lane>>4)*4+j
    #pragma unroll
    for (int m = 0; m < MF; ++m) {
      #pragma unroll
      for (int n = 0; n < 4; ++n) {
        int col = tnBase + wc + n * 16 + lr;
        #pragma unroll
        for (int j = 0; j < 4; ++j) {
          int row = rb0 + m * 16 + j;
          float v = acc[m][n][j];
          size_t idx = (size_t)row * ldc + col;
          if constexpr (EPI == 1) {
            Cf[idx] = v;
          } else if constexpr (EPI == 2) {
            Ch[idx] = f2bf(v + bf2f(R[idx]));
          } else {
            Ch[idx] = f2bf(v);
          }
        }
      }
    }
  }
}

// ---------------- fallback sentinel ----------------
__global__ void fill_kernel(float* out, int n, float v) {
  int i = blockIdx.x * blockDim.x + threadIdx.x;
  for (; i < n; i += gridDim.x * blockDim.x) out[i] = v;
}

extern "C" void kernel_launch(void* const* d_in, const int* in_sizes, int n_in,
                              void* d_out, int out_size, void* d_ws, size_t ws_size,
                              hipStream_t stream) {
  const float* x  = (const float*)d_in[0];
  const float* W1 = (const float*)d_in[1];
  const float* W2 = (const float*)d_in[2];
  const float* W3 = (const float*)d_in[3];
  float* out = (float*)d_out;

  char* ws = (char*)d_ws;
  size_t off = 0;
  auto alloc = [&](size_t bytes) -> char* {
    char* p = ws + off;
    off += (bytes + 255) & ~(size_t)255;
    return p;
  };

  // ---- persistent buffers (~81MB) ----
  unsigned short* zb  = (unsigned short*)alloc((size_t)MROWS * PDIM * 2);      // 16MB
  unsigned short* kvb = (unsigned short*)alloc((size_t)MROWS * 2 * PDIM * 2);  // 32MB
  unsigned short* vt  = (unsigned short*)alloc((size_t)BATCH * PDIM * L_SEQ * 2); // 16MB
  unsigned short* ar  = (unsigned short*)alloc((size_t)MROWS * PDIM * 2);      // 16MB
  unsigned short* w3b = (unsigned short*)alloc((size_t)DOUT * PDIM * 2);       // 1MB
  size_t persist = off;

  // ---- transient scratch region: converts first, then bf16 scores ----
  char* scratch = ws + persist;
  size_t avail = (ws_size > persist) ? (ws_size - persist) : 0;

  size_t xbB  = ((size_t)MROWS * DIN * 2 + 255) & ~(size_t)255;   // 32MB
  size_t w1B  = ((size_t)PDIM * DIN * 2 + 255) & ~(size_t)255;    // 1MB
  size_t w2B  = ((size_t)2 * PDIM * PDIM * 2 + 255) & ~(size_t)255; // 2MB
  size_t convNeed = xbB + w1B + w2B;                              // ~35MB

  size_t scores1 = ((size_t)L_SEQ * L_SEQ * 2 + 255) & ~(size_t)255; // 8MB bf16
  size_t per = scores1;                                           // probs in-place

  if (avail < convNeed || avail < per) {
    float sentinel = 1.0e6f + (float)(ws_size >> 20);
    fill_kernel<<<512, 256, 0, stream>>>(out, out_size, sentinel);
    return;
  }

  // chunking: c batches of attention scratch at a time, balanced chunks
  int c = (int)(avail / per);
  if (c > BATCH) c = BATCH;
  int nch = (BATCH + c - 1) / c;
  c = (BATCH + nch - 1) / nch;   // balance (e.g. 6 -> 4,4)

  unsigned short* xb  = (unsigned short*)(scratch);
  unsigned short* w1b = (unsigned short*)(scratch + xbB);
  unsigned short* w2b = (unsigned short*)(scratch + xbB + w1B);
  // bf16 scores overlap the convert buffers (consumed before QK^T runs);
  // probs are written in-place over the score rows by softmax
  unsigned short* scores = (unsigned short*)(scratch);

  const float scaling = 0.04419417382415922f;  // 512^-0.5
  const int NTRI = (L_SEQ / BM) * (L_SEQ / BM + 1) / 2;   // 136 lower-tri tiles

  // converts
  convert_f32_bf16<<<2048, 256, 0, stream>>>(x,  xb,  (MROWS * DIN) / 4);
  convert_f32_bf16<<<512,  256, 0, stream>>>(W1, w1b, (PDIM * DIN) / 4);
  convert_f32_bf16<<<512,  256, 0, stream>>>(W2, w2b, (2 * PDIM * PDIM) / 4);
  convert_f32_bf16<<<512,  256, 0, stream>>>(W3, w3b, (DOUT * PDIM) / 4);

  // GEMM1: z = x @ W1^T   [16384,1024]x[512,1024] -> [16384,512] bf16
  gemm_bt<0, 128><<<dim3(PDIM / 128, MROWS / BM, 1), 256, 0, stream>>>(
      xb, w1b, zb, zb, MROWS, PDIM, DIN, DIN, DIN, PDIM, 0, 0, 0, 0, 0);

  // GEMM2: kv = z @ W2^T  [16384,512]x[1024,512] -> [16384,1024] bf16
  gemm_bt<0, 128><<<dim3(2 * PDIM / 128, MROWS / BM, 1), 256, 0, stream>>>(
      zb, w2b, kvb, zb, MROWS, 2 * PDIM, PDIM, PDIM, PDIM, 2 * PDIM, 0, 0, 0, 0, 0);

  // V transpose per batch: vt[b][p][l]
  transpose_v_kernel<<<dim3(L_SEQ / 32, PDIM / 32, BATCH), dim3(32, 8), 0, stream>>>(kvb, vt);

  // ---- chunked attention (c==8 expected: single pass) ----
  for (int b0 = 0; b0 < BATCH; b0 += c) {
    int cb = (BATCH - b0 < c) ? (BATCH - b0) : c;

    // scores[z] = Q @ K^T (bf16), triangular tile enumeration (mode 1)
    gemm_bt<0, 128><<<dim3(NTRI, 1, cb), 256, 0, stream>>>(
        zb + (size_t)b0 * PDIM, kvb + (size_t)b0 * 2 * PDIM, scores, zb,
        L_SEQ, L_SEQ, PDIM, BATCH * PDIM, BATCH * 2 * PDIM, L_SEQ,
        (size_t)PDIM, (size_t)2 * PDIM, (size_t)L_SEQ * L_SEQ, 0, 1);

    softmax_causal<<<dim3(L_SEQ, 1, cb), 256, 0, stream>>>(
        scores, (size_t)L_SEQ * L_SEQ, scaling);

    // attn_out + residual -> ar (bf16), causal-paired rows (mode 2), BN=64
    gemm_bt<2, 64><<<dim3(PDIM / 64, L_SEQ / BM / 2, cb), 256, 0, stream>>>(
        scores, vt + (size_t)b0 * PDIM * L_SEQ, ar + (size_t)b0 * PDIM,
        zb + (size_t)b0 * PDIM,
        L_SEQ, PDIM, L_SEQ, L_SEQ, L_SEQ, BATCH * PDIM,
        (size_t)L_SEQ * L_SEQ, (size_t)PDIM * L_SEQ, (size_t)PDIM, (size_t)PDIM, 2);
  }

  // GEMM3: out = (attn + residual) @ W3^T -> fp32 d_out
  gemm_bt<1, 128><<<dim3(DOUT / 128, MROWS / BM, 1), 256, 0, stream>>>(
      ar, w3b, out, zb, MROWS, DOUT, PDIM, PDIM, PDIM, DOUT, 0, 0, 0, 0, 0);
}